// Round 5
// baseline (367.908 us; speedup 1.0000x reference)
//
#include <hip/hip_runtime.h>
#include <hip/hip_bf16.h>
#include <stdint.h>

#define NB   16
#define CIN  256
#define CRED 64
#define HW   2304
#define NIG  4    // i-dimension split groups
#define NIT  9    // i-tiles per group (36/4)

typedef __bf16 bf16;
typedef __bf16 bf16x8 __attribute__((ext_vector_type(8)));
typedef __bf16 bf16x4 __attribute__((ext_vector_type(4)));
typedef float  f32x4  __attribute__((ext_vector_type(4)));

// ---------------- Kernel 0: weight prep (fp32 -> bf16; Wq,bq scaled by 1/ln2) ------
__global__ __launch_bounds__(256) void prep_kernel(
    const float* __restrict__ Wq, const float* __restrict__ bq,
    const float* __restrict__ Wk, const float* __restrict__ Wv,
    const float* __restrict__ Watt,
    bf16* __restrict__ Wqb, bf16* __restrict__ Wkb, bf16* __restrict__ Wvb,
    bf16* __restrict__ Wab, float* __restrict__ bqs)
{
    const float INVLN2 = 1.44269504088896f;
    int i = blockIdx.x * 256 + threadIdx.x;   // 64 blocks -> 16384 threads
    Wqb[i] = (bf16)(Wq[i] * INVLN2);
    Wkb[i] = (bf16)Wk[i];
    Wvb[i] = (bf16)Wv[i];
    Wab[i] = (bf16)Watt[i];
    if (i < CRED) bqs[i] = bq[i] * INVLN2;
}

// ---------------- Kernel 1: fused QKV 1x1 convs, 32-pos j-tiles, bf16 weights ------
// x [N][256][2304] f32 -> qT [N][2304][64] (q/ln2), kT [N][2304][64], v [N][64][2304]
__global__ __launch_bounds__(256) void qkv_kernel(
    const float* __restrict__ x,
    const bf16* __restrict__ Wqb, const float* __restrict__ bqs,
    const bf16* __restrict__ Wkb, const float* __restrict__ bk,
    const bf16* __restrict__ Wvb, const float* __restrict__ bv,
    bf16* __restrict__ qT, bf16* __restrict__ kT, bf16* __restrict__ v)
{
    __shared__ __align__(16) bf16 sX[32 * 264];  // xT[pos][cin], stride 264 (pad 8)
    const int jt = blockIdx.x, n = blockIdx.y;
    const int jbase = jt * 32;
    const int tid = threadIdx.x;
    const int lane = tid & 63, w = tid >> 6;
    const int l15 = lane & 15, q4 = lane >> 4;

    const float* xn = x + ((size_t)n * CIN) * HW + jbase;
    #pragma unroll
    for (int it = 0; it < 8; ++it) {
        int idx = tid + 256 * it;          // 2048 float4s total
        int c = idx >> 3, p4 = idx & 7;
        const float4 vv = *(const float4*)(xn + c * HW + p4 * 4);
        sX[(p4 * 4 + 0) * 264 + c] = (bf16)vv.x;
        sX[(p4 * 4 + 1) * 264 + c] = (bf16)vv.y;
        sX[(p4 * 4 + 2) * 264 + c] = (bf16)vv.z;
        sX[(p4 * 4 + 3) * 264 + c] = (bf16)vv.w;
    }
    __syncthreads();

    const bf16*  Ws[3] = {Wqb, Wkb, Wvb};
    const float* bs[3] = {bqs, bk, bv};
    #pragma unroll
    for (int wi = 0; wi < 3; ++wi) {
        bf16x8 a[8];
        const bf16* Wp = Ws[wi] + (w * 16 + l15) * CIN + q4 * 8;
        #pragma unroll
        for (int ks = 0; ks < 8; ++ks) a[ks] = *(const bf16x8*)(Wp + ks * 32);
        f32x4 acc[2] = {};
        #pragma unroll
        for (int nt = 0; nt < 2; ++nt) {
            #pragma unroll
            for (int ks = 0; ks < 8; ++ks) {
                bf16x8 b = *(const bf16x8*)(sX + (nt * 16 + l15) * 264 + ks * 32 + q4 * 8);
                acc[nt] = __builtin_amdgcn_mfma_f32_16x16x32_bf16(a[ks], b, acc[nt], 0, 0, 0);
            }
        }
        const int crb = w * 16 + q4 * 4;   // C/D row = outc
        const float b0 = bs[wi][crb], b1 = bs[wi][crb + 1],
                    b2 = bs[wi][crb + 2], b3 = bs[wi][crb + 3];
        if (wi < 2) {
            bf16* dst = (wi == 0 ? qT : kT) + ((size_t)n * HW) * 64;
            #pragma unroll
            for (int nt = 0; nt < 2; ++nt) {
                int pos = jbase + nt * 16 + l15;
                bf16x4 pk = {(bf16)(acc[nt].x + b0), (bf16)(acc[nt].y + b1),
                             (bf16)(acc[nt].z + b2), (bf16)(acc[nt].w + b3)};
                *(bf16x4*)(dst + pos * 64 + crb) = pk;
            }
        } else {
            bf16* dst = v + ((size_t)n * CRED) * HW;
            #pragma unroll
            for (int nt = 0; nt < 2; ++nt) {
                int pos = jbase + nt * 16 + l15;
                dst[(crb + 0) * HW + pos] = (bf16)(acc[nt].x + b0);
                dst[(crb + 1) * HW + pos] = (bf16)(acc[nt].y + b1);
                dst[(crb + 2) * HW + pos] = (bf16)(acc[nt].z + b2);
                dst[(crb + 3) * HW + pos] = (bf16)(acc[nt].w + b3);
            }
        }
    }
}

// ---------------- Kernel 2: fused KtQ -> exp2 -> V*P ----------------
// 512 threads (8 waves), 128-j tiles, i-split 4 ways. qT holds q/ln2 -> P=exp2(S').
// LDS: sP 128x72 (Q then P) + sK 64x72 + sV 64x72 = 36 KB -> 4 blocks/CU, 32 waves/CU.
// Partial O written as bf16 (unnormalized); out_kernel folds the sum into its GEMM.
__global__ __launch_bounds__(512, 8) void attn_kernel(
    const bf16* __restrict__ qT, const bf16* __restrict__ kT,
    const bf16* __restrict__ v,
    bf16* __restrict__ OTp, float* __restrict__ Z)
{
    __shared__ __align__(16) bf16 sP[128 * 72];  // Q during preload, then P
    __shared__ __align__(16) bf16 sK[64 * 72];
    __shared__ __align__(16) bf16 sV[64 * 72];
    const int jt = blockIdx.x, ig = blockIdx.y, n = blockIdx.z;
    const int jbase = jt * 128;
    const int tid = threadIdx.x;
    const int lane = tid & 63, w = tid >> 6;     // 8 waves
    const int l15 = lane & 15, q4 = lane >> 4;
    const int wi = w & 3;                        // i-row group (16 rows of the 64-i tile)
    const int jh = w >> 2;                       // j-half (64 of the 128-j tile)

    // stage Q tile (128 rows x 8 uint4)
    {
        const uint4* src = (const uint4*)(qT + ((size_t)n * HW + jbase) * 64);
        uint4* dst = (uint4*)sP;
        #pragma unroll
        for (int i = tid; i < 1024; i += 512) {
            int r = i >> 3, c = i & 7;
            dst[r * 9 + c] = src[r * 8 + c];
        }
    }
    __syncthreads();
    // loop-invariant Q fragments -> registers (wave's own j-half)
    bf16x8 qf[4][2];
    #pragma unroll
    for (int nt = 0; nt < 4; ++nt)
        #pragma unroll
        for (int ks = 0; ks < 2; ++ks)
            qf[nt][ks] = *(const bf16x8*)(sP + (jh * 64 + nt * 16 + l15) * 72 + ks * 32 + q4 * 8);

    f32x4 oacc[4] = {};
    float zacc = 0.f;
    const uint4* ksrc = (const uint4*)(kT + ((size_t)n * HW) * 64);
    const bf16* vbase = v + ((size_t)n * CRED) * HW;
    const int r0 = tid >> 3, c0 = tid & 7;       // 512 threads -> one uint4 each per array

    for (int it = 0; it < NIT; ++it) {
        const int ibase = (ig * NIT + it) * 64;
        __syncthreads();   // everyone done with prev sK/sV/sP
        ((uint4*)sK)[r0 * 9 + c0] = ksrc[(ibase + r0) * 8 + c0];
        ((uint4*)sV)[r0 * 9 + c0] = *(const uint4*)(vbase + (size_t)r0 * HW + ibase + c0 * 8);
        __syncthreads();

        // S' = (K_i^T Q_j)/ln2 : wave owns i-rows [16wi,16wi+16), j in its 64-half
        bf16x8 kf0 = *(const bf16x8*)(sK + (wi * 16 + l15) * 72 + q4 * 8);
        bf16x8 kf1 = *(const bf16x8*)(sK + (wi * 16 + l15) * 72 + 32 + q4 * 8);
        #pragma unroll
        for (int nt = 0; nt < 4; ++nt) {
            f32x4 accs = {};
            accs = __builtin_amdgcn_mfma_f32_16x16x32_bf16(kf0, qf[nt][0], accs, 0, 0, 0);
            accs = __builtin_amdgcn_mfma_f32_16x16x32_bf16(kf1, qf[nt][1], accs, 0, 0, 0);
            float p0 = exp2f(accs.x), p1 = exp2f(accs.y);
            float p2 = exp2f(accs.z), p3 = exp2f(accs.w);
            zacc += (p0 + p1) + (p2 + p3);
            bf16x4 pk = {(bf16)p0, (bf16)p1, (bf16)p2, (bf16)p3};
            *(bf16x4*)(sP + (jh * 64 + nt * 16 + l15) * 72 + wi * 16 + q4 * 4) = pk;
        }
        __syncthreads();   // P visible
        // O += V_i * P : wave owns c-rows [16wi,16wi+16), j in its 64-half
        bf16x8 vf0 = *(const bf16x8*)(sV + (wi * 16 + l15) * 72 + q4 * 8);
        bf16x8 vf1 = *(const bf16x8*)(sV + (wi * 16 + l15) * 72 + 32 + q4 * 8);
        #pragma unroll
        for (int nt = 0; nt < 4; ++nt) {
            bf16x8 p0 = *(const bf16x8*)(sP + (jh * 64 + nt * 16 + l15) * 72 + q4 * 8);
            bf16x8 p1 = *(const bf16x8*)(sP + (jh * 64 + nt * 16 + l15) * 72 + 32 + q4 * 8);
            oacc[nt] = __builtin_amdgcn_mfma_f32_16x16x32_bf16(vf0, p0, oacc[nt], 0, 0, 0);
            oacc[nt] = __builtin_amdgcn_mfma_f32_16x16x32_bf16(vf1, p1, oacc[nt], 0, 0, 0);
        }
    }
    // write unnormalized bf16 partial O transposed: OTp[ig][n][pos][cr]
    bf16* OTn = OTp + (((size_t)ig * NB + n) * HW) * 64;
    #pragma unroll
    for (int nt = 0; nt < 4; ++nt) {
        int pos = jbase + jh * 64 + nt * 16 + l15;
        bf16x4 o = {(bf16)oacc[nt].x, (bf16)oacc[nt].y, (bf16)oacc[nt].z, (bf16)oacc[nt].w};
        *(bf16x4*)(OTn + pos * 64 + wi * 16 + q4 * 4) = o;
    }
    #pragma unroll
    for (int off = 32; off > 0; off >>= 1) zacc += __shfl_down(zacc, off);
    if (lane == 0) atomicAdd(Z + n, zacc);
}

// ---------------- Kernel 3: out = g * (Watt @ (sum_ig O_ig) * invZ + batt + 1) -------
// 32-pos tiles: grid (72, 16). MFMA accumulates over the NIG partials (K-extension).
__global__ __launch_bounds__(256) void out_kernel(
    const bf16* __restrict__ OTp, const float* __restrict__ Z,
    const bf16* __restrict__ Wab, const float* __restrict__ batt,
    const float* __restrict__ g, float* __restrict__ out)
{
    __shared__ __align__(16) bf16 sO[NIG * 32 * 72];  // [ig][pos][cr]
    const int jt = blockIdx.x, n = blockIdx.y;
    const int jbase = jt * 32;
    const int tid = threadIdx.x;
    const int lane = tid & 63, w = tid >> 6;
    const int l15 = lane & 15, q4 = lane >> 4;
    const float invZ = 1.0f / Z[n];

    // hoist weights (independent of staging): wave w owns co [64w, 64w+64)
    bf16x8 a[4][2];
    #pragma unroll
    for (int mt = 0; mt < 4; ++mt)
        #pragma unroll
        for (int ks = 0; ks < 2; ++ks)
            a[mt][ks] = *(const bf16x8*)(Wab + (w * 64 + mt * 16 + l15) * 64 + ks * 32 + q4 * 8);

    // stage 4 partial tiles: 1024 uint4 over 256 threads
    #pragma unroll
    for (int i = tid; i < 1024; i += 256) {
        int ig = i >> 8, rem = i & 255, r = rem >> 3, c = rem & 7;
        ((uint4*)sO)[(ig * 32 + r) * 9 + c] =
            ((const uint4*)OTp)[(((size_t)ig * NB + n) * HW + jbase + r) * 8 + c];
    }
    __syncthreads();

    f32x4 acc[4][2] = {};   // [mt][nt]
    #pragma unroll
    for (int ig = 0; ig < NIG; ++ig) {
        bf16x8 b[2][2];
        #pragma unroll
        for (int nt = 0; nt < 2; ++nt)
            #pragma unroll
            for (int ks = 0; ks < 2; ++ks)
                b[nt][ks] = *(const bf16x8*)(sO + (ig * 32 + nt * 16 + l15) * 72 + ks * 32 + q4 * 8);
        #pragma unroll
        for (int mt = 0; mt < 4; ++mt)
            #pragma unroll
            for (int nt = 0; nt < 2; ++nt) {
                acc[mt][nt] = __builtin_amdgcn_mfma_f32_16x16x32_bf16(a[mt][0], b[nt][0], acc[mt][nt], 0, 0, 0);
                acc[mt][nt] = __builtin_amdgcn_mfma_f32_16x16x32_bf16(a[mt][1], b[nt][1], acc[mt][nt], 0, 0, 0);
            }
    }

    const float* gp = g + ((size_t)n * CIN) * HW;
    float* op = out + ((size_t)n * CIN) * HW;
    #pragma unroll
    for (int mt = 0; mt < 4; ++mt) {
        const int co = w * 64 + mt * 16 + q4 * 4;
        const float c0 = batt[co], c1 = batt[co + 1], c2 = batt[co + 2], c3 = batt[co + 3];
        #pragma unroll
        for (int nt = 0; nt < 2; ++nt) {
            const int pos = jbase + nt * 16 + l15;
            const float g0 = gp[(co + 0) * HW + pos], g1 = gp[(co + 1) * HW + pos];
            const float g2 = gp[(co + 2) * HW + pos], g3 = gp[(co + 3) * HW + pos];
            op[(co + 0) * HW + pos] = g0 * (acc[mt][nt].x * invZ + c0 + 1.0f);
            op[(co + 1) * HW + pos] = g1 * (acc[mt][nt].y * invZ + c1 + 1.0f);
            op[(co + 2) * HW + pos] = g2 * (acc[mt][nt].z * invZ + c2 + 1.0f);
            op[(co + 3) * HW + pos] = g3 * (acc[mt][nt].w * invZ + c3 + 1.0f);
        }
    }
}

extern "C" void kernel_launch(void* const* d_in, const int* in_sizes, int n_in,
                              void* d_out, int out_size, void* d_ws, size_t ws_size,
                              hipStream_t stream) {
    const float* x    = (const float*)d_in[0];
    const float* g    = (const float*)d_in[1];
    const float* Wq   = (const float*)d_in[2];
    const float* bq   = (const float*)d_in[3];
    const float* Wk   = (const float*)d_in[4];
    const float* bk   = (const float*)d_in[5];
    const float* Wv   = (const float*)d_in[6];
    const float* bv   = (const float*)d_in[7];
    const float* Watt = (const float*)d_in[8];
    const float* batt = (const float*)d_in[9];
    float* out = (float*)d_out;

    char* ws = (char*)d_ws;
    const size_t qkv_sz = (size_t)NB * HW * CRED * sizeof(bf16);   // 4,718,592 B
    bf16*  qT  = (bf16*)(ws);
    bf16*  kT  = (bf16*)(ws + qkv_sz);
    bf16*  vv  = (bf16*)(ws + 2 * qkv_sz);
    bf16*  OTp = (bf16*)(ws + 3 * qkv_sz);                         // NIG x 4,718,592 B
    char*  w2  = ws + (3 + NIG) * qkv_sz;
    float* Zp  = (float*)(w2);
    bf16*  Wqb = (bf16*)(w2 + 256);
    bf16*  Wkb = Wqb + CRED * CIN;
    bf16*  Wvb = Wkb + CRED * CIN;
    bf16*  Wab = Wvb + CRED * CIN;
    float* bqs = (float*)(Wab + CIN * CRED);

    hipMemsetAsync(Zp, 0, NB * sizeof(float), stream);

    prep_kernel<<<dim3(64), dim3(256), 0, stream>>>(Wq, bq, Wk, Wv, Watt, Wqb, Wkb, Wvb, Wab, bqs);
    qkv_kernel<<<dim3(HW / 32, NB), dim3(256), 0, stream>>>(x, Wqb, bqs, Wkb, bk, Wvb, bv, qT, kT, vv);
    attn_kernel<<<dim3(HW / 128, NIG, NB), dim3(512), 0, stream>>>(qT, kT, vv, OTp, Zp);
    out_kernel<<<dim3(HW / 32, NB), dim3(256), 0, stream>>>(OTp, Zp, Wab, batt, g, out);
}

// Round 6
// 296.976 us; speedup vs baseline: 1.2388x; 1.2388x over previous
//
#include <hip/hip_runtime.h>
#include <hip/hip_bf16.h>
#include <stdint.h>

#define NB   16
#define CIN  256
#define CRED 64
#define HW   2304
#define NIG  4    // i-dimension split groups
#define NIT  9    // i-tiles per group (36/4)

typedef __bf16 bf16;
typedef __bf16 bf16x8 __attribute__((ext_vector_type(8)));
typedef __bf16 bf16x4 __attribute__((ext_vector_type(4)));
typedef __bf16 bf16x2 __attribute__((ext_vector_type(2)));
typedef float  f32x4  __attribute__((ext_vector_type(4)));
typedef short  short4v __attribute__((ext_vector_type(4)));

// ---------------- Kernel 0: weight prep (fp32 -> bf16; Wq,bq scaled by 1/ln2) ------
__global__ __launch_bounds__(256) void prep_kernel(
    const float* __restrict__ Wq, const float* __restrict__ bq,
    const float* __restrict__ Wk, const float* __restrict__ Wv,
    const float* __restrict__ Watt,
    bf16* __restrict__ Wqb, bf16* __restrict__ Wkb, bf16* __restrict__ Wvb,
    bf16* __restrict__ Wab, float* __restrict__ bqs)
{
    const float INVLN2 = 1.44269504088896f;
    int i = blockIdx.x * 256 + threadIdx.x;   // 64 blocks -> 16384 threads
    Wqb[i] = (bf16)(Wq[i] * INVLN2);
    Wkb[i] = (bf16)Wk[i];
    Wvb[i] = (bf16)Wv[i];
    Wab[i] = (bf16)Watt[i];
    if (i < CRED) bqs[i] = bq[i] * INVLN2;
}

// ---------------- Kernel 1: fused QKV 1x1 convs, 32-pos j-tiles, bf16 weights ------
// x [N][256][2304] f32 -> qT [N][2304][64] (q/ln2), kT [N][2304][64], v [N][64][2304]
__global__ __launch_bounds__(256) void qkv_kernel(
    const float* __restrict__ x,
    const bf16* __restrict__ Wqb, const float* __restrict__ bqs,
    const bf16* __restrict__ Wkb, const float* __restrict__ bk,
    const bf16* __restrict__ Wvb, const float* __restrict__ bv,
    bf16* __restrict__ qT, bf16* __restrict__ kT, bf16* __restrict__ v)
{
    __shared__ __align__(16) bf16 sX[32 * 264];  // xT[pos][cin], stride 264 (pad 8)
    const int jt = blockIdx.x, n = blockIdx.y;
    const int jbase = jt * 32;
    const int tid = threadIdx.x;
    const int lane = tid & 63, w = tid >> 6;
    const int l15 = lane & 15, q4 = lane >> 4;

    // stage xT: channel-pair loads -> packed bf16x2 LDS writes (b32, not scalar b16)
    const float* xn = x + ((size_t)n * CIN) * HW + jbase;
    #pragma unroll
    for (int itl = 0; itl < 4; ++itl) {
        int idx = tid + 256 * itl;         // 1024 pair-items: c2 (128) x p4 (8)
        int c2 = idx >> 3, p4 = idx & 7;
        int c = c2 * 2;
        const float4 va = *(const float4*)(xn + (size_t)c * HW + p4 * 4);
        const float4 vb = *(const float4*)(xn + (size_t)(c + 1) * HW + p4 * 4);
        bf16x2 t0 = {(bf16)va.x, (bf16)vb.x};
        bf16x2 t1 = {(bf16)va.y, (bf16)vb.y};
        bf16x2 t2 = {(bf16)va.z, (bf16)vb.z};
        bf16x2 t3 = {(bf16)va.w, (bf16)vb.w};
        *(bf16x2*)(sX + (p4 * 4 + 0) * 264 + c) = t0;
        *(bf16x2*)(sX + (p4 * 4 + 1) * 264 + c) = t1;
        *(bf16x2*)(sX + (p4 * 4 + 2) * 264 + c) = t2;
        *(bf16x2*)(sX + (p4 * 4 + 3) * 264 + c) = t3;
    }
    __syncthreads();

    const bf16*  Ws[3] = {Wqb, Wkb, Wvb};
    const float* bs[3] = {bqs, bk, bv};
    #pragma unroll
    for (int wi = 0; wi < 3; ++wi) {
        bf16x8 a[8];
        const bf16* Wp = Ws[wi] + (w * 16 + l15) * CIN + q4 * 8;
        #pragma unroll
        for (int ks = 0; ks < 8; ++ks) a[ks] = *(const bf16x8*)(Wp + ks * 32);
        f32x4 acc[2] = {};
        #pragma unroll
        for (int nt = 0; nt < 2; ++nt) {
            #pragma unroll
            for (int ks = 0; ks < 8; ++ks) {
                bf16x8 b = *(const bf16x8*)(sX + (nt * 16 + l15) * 264 + ks * 32 + q4 * 8);
                acc[nt] = __builtin_amdgcn_mfma_f32_16x16x32_bf16(a[ks], b, acc[nt], 0, 0, 0);
            }
        }
        const int crb = w * 16 + q4 * 4;   // C/D row = outc
        const float b0 = bs[wi][crb], b1 = bs[wi][crb + 1],
                    b2 = bs[wi][crb + 2], b3 = bs[wi][crb + 3];
        if (wi < 2) {
            bf16* dst = (wi == 0 ? qT : kT) + ((size_t)n * HW) * 64;
            #pragma unroll
            for (int nt = 0; nt < 2; ++nt) {
                int pos = jbase + nt * 16 + l15;
                bf16x4 pk = {(bf16)(acc[nt].x + b0), (bf16)(acc[nt].y + b1),
                             (bf16)(acc[nt].z + b2), (bf16)(acc[nt].w + b3)};
                *(bf16x4*)(dst + pos * 64 + crb) = pk;
            }
        } else {
            bf16* dst = v + ((size_t)n * CRED) * HW;
            #pragma unroll
            for (int nt = 0; nt < 2; ++nt) {
                int pos = jbase + nt * 16 + l15;
                dst[(crb + 0) * HW + pos] = (bf16)(acc[nt].x + b0);
                dst[(crb + 1) * HW + pos] = (bf16)(acc[nt].y + b1);
                dst[(crb + 2) * HW + pos] = (bf16)(acc[nt].z + b2);
                dst[(crb + 3) * HW + pos] = (bf16)(acc[nt].w + b3);
            }
        }
    }
}

// ---------------- Kernel 2: fused KtQ -> exp2 -> V*P, in-register P ----------------
// Each wave owns 16 j-columns. S C-frag (row=q4*4+r) == 16x16x16 B-frag (k=q4*4+jj),
// so P goes straight from exp into the PV MFMA: no LDS round-trip, ONE barrier/iter.
// K/V double-buffered in LDS (2x18KB = 36.8 KB -> 4 blocks/CU).
__global__ __launch_bounds__(256, 4) void attn_kernel(
    const bf16* __restrict__ qT, const bf16* __restrict__ kT,
    const bf16* __restrict__ v,
    bf16* __restrict__ OTp, float* __restrict__ Z)
{
    __shared__ __align__(16) bf16 sK[2][64 * 72];
    __shared__ __align__(16) bf16 sV[2][64 * 72];
    const int jt = blockIdx.x, ig = blockIdx.y, n = blockIdx.z;
    const int tid = threadIdx.x;
    const int lane = tid & 63, wv = tid >> 6;
    const int l15 = lane & 15, q4 = lane >> 4;
    const int j = jt * 64 + wv * 16 + l15;    // this lane's j column

    // Q B-frags direct from global (loop-invariant; qT rows contiguous)
    const bf16* qrow = qT + ((size_t)n * HW + j) * 64;
    bf16x8 qf0 = *(const bf16x8*)(qrow + q4 * 8);
    bf16x8 qf1 = *(const bf16x8*)(qrow + 32 + q4 * 8);

    const uint4* ksrc = (const uint4*)(kT + ((size_t)n * HW) * 64);
    const bf16* vbase = v + ((size_t)n * CRED) * HW;
    const int r0 = tid >> 3, c0 = tid & 7;   // staging rows r0, r0+32; uint4-col c0

    // prologue: tile 0 -> buf0
    const int ib0 = ig * NIT * 64;
    uint4 kr0 = ksrc[(size_t)(ib0 + r0) * 8 + c0];
    uint4 kr1 = ksrc[(size_t)(ib0 + r0 + 32) * 8 + c0];
    uint4 vr0 = *(const uint4*)(vbase + (size_t)r0 * HW + ib0 + c0 * 8);
    uint4 vr1 = *(const uint4*)(vbase + (size_t)(r0 + 32) * HW + ib0 + c0 * 8);
    ((uint4*)sK[0])[r0 * 9 + c0] = kr0;
    ((uint4*)sK[0])[(r0 + 32) * 9 + c0] = kr1;
    ((uint4*)sV[0])[r0 * 9 + c0] = vr0;
    ((uint4*)sV[0])[(r0 + 32) * 9 + c0] = vr1;
    __syncthreads();

    f32x4 oacc[4] = {};
    float zacc = 0.f;

    for (int it = 0; it < NIT; ++it) {
        const bf16* bK = sK[it & 1];
        const bf16* bV = sV[it & 1];
        // issue next tile's global loads now; they fly during the compute phase
        if (it + 1 < NIT) {
            const int nb = ib0 + (it + 1) * 64;
            kr0 = ksrc[(size_t)(nb + r0) * 8 + c0];
            kr1 = ksrc[(size_t)(nb + r0 + 32) * 8 + c0];
            vr0 = *(const uint4*)(vbase + (size_t)r0 * HW + nb + c0 * 8);
            vr1 = *(const uint4*)(vbase + (size_t)(r0 + 32) * HW + nb + c0 * 8);
        }
        // S (K=32) per 16-i tile -> exp2 -> PV (K=16) with P in-register
        #pragma unroll
        for (int mt = 0; mt < 4; ++mt) {
            bf16x8 kf0 = *(const bf16x8*)(bK + (mt * 16 + l15) * 72 + q4 * 8);
            bf16x8 kf1 = *(const bf16x8*)(bK + (mt * 16 + l15) * 72 + 32 + q4 * 8);
            f32x4 s = {};
            s = __builtin_amdgcn_mfma_f32_16x16x32_bf16(kf0, qf0, s, 0, 0, 0);
            s = __builtin_amdgcn_mfma_f32_16x16x32_bf16(kf1, qf1, s, 0, 0, 0);
            float p0 = exp2f(s.x), p1 = exp2f(s.y), p2 = exp2f(s.z), p3 = exp2f(s.w);
            zacc += (p0 + p1) + (p2 + p3);
            bf16x4 pk = {(bf16)p0, (bf16)p1, (bf16)p2, (bf16)p3};
            short4v pb = *(short4v*)&pk;    // B-frag for 16x16x16: k = q4*4+jj == C rows
            #pragma unroll
            for (int ct = 0; ct < 4; ++ct) {
                short4v vf = *(const short4v*)(bV + (ct * 16 + l15) * 72 + mt * 16 + q4 * 4);
                oacc[ct] = __builtin_amdgcn_mfma_f32_16x16x16bf16_1k(vf, pb, oacc[ct], 0, 0, 0);
            }
        }
        // commit prefetched tile (vmcnt wait has a full compute phase of slack)
        if (it + 1 < NIT) {
            uint4* dK = (uint4*)sK[(it + 1) & 1];
            uint4* dV = (uint4*)sV[(it + 1) & 1];
            dK[r0 * 9 + c0] = kr0;
            dK[(r0 + 32) * 9 + c0] = kr1;
            dV[r0 * 9 + c0] = vr0;
            dV[(r0 + 32) * 9 + c0] = vr1;
            __syncthreads();
        }
    }
    // write unnormalized bf16 partial O transposed: OTp[ig][n][pos][cr]
    bf16* OTn = OTp + (((size_t)ig * NB + n) * HW) * 64;
    #pragma unroll
    for (int ct = 0; ct < 4; ++ct) {
        bf16x4 o = {(bf16)oacc[ct].x, (bf16)oacc[ct].y, (bf16)oacc[ct].z, (bf16)oacc[ct].w};
        *(bf16x4*)(OTn + (size_t)j * 64 + ct * 16 + q4 * 4) = o;
    }
    // per-batch Z: wave reduce then one atomic per wave
    #pragma unroll
    for (int off = 32; off > 0; off >>= 1) zacc += __shfl_down(zacc, off);
    if (lane == 0) atomicAdd(Z + n, zacc);
}

// ---------------- Kernel 3: out = g * (Watt @ (sum_ig O_ig) * invZ + batt + 1) -------
// 32-pos tiles: grid (72, 16). MFMA accumulates over the NIG partials (K-extension).
__global__ __launch_bounds__(256) void out_kernel(
    const bf16* __restrict__ OTp, const float* __restrict__ Z,
    const bf16* __restrict__ Wab, const float* __restrict__ batt,
    const float* __restrict__ g, float* __restrict__ out)
{
    __shared__ __align__(16) bf16 sO[NIG * 32 * 72];  // [ig][pos][cr]
    const int jt = blockIdx.x, n = blockIdx.y;
    const int jbase = jt * 32;
    const int tid = threadIdx.x;
    const int lane = tid & 63, w = tid >> 6;
    const int l15 = lane & 15, q4 = lane >> 4;
    const float invZ = 1.0f / Z[n];

    // hoist weights: wave w owns co [64w, 64w+64)
    bf16x8 a[4][2];
    #pragma unroll
    for (int mt = 0; mt < 4; ++mt)
        #pragma unroll
        for (int ks = 0; ks < 2; ++ks)
            a[mt][ks] = *(const bf16x8*)(Wab + (w * 64 + mt * 16 + l15) * 64 + ks * 32 + q4 * 8);

    // stage 4 partial tiles: 1024 uint4 over 256 threads
    #pragma unroll
    for (int i = tid; i < 1024; i += 256) {
        int ig = i >> 8, rem = i & 255, r = rem >> 3, c = rem & 7;
        ((uint4*)sO)[(ig * 32 + r) * 9 + c] =
            ((const uint4*)OTp)[(((size_t)ig * NB + n) * HW + jbase + r) * 8 + c];
    }
    __syncthreads();

    f32x4 acc[4][2] = {};   // [mt][nt]
    #pragma unroll
    for (int ig = 0; ig < NIG; ++ig) {
        bf16x8 b[2][2];
        #pragma unroll
        for (int nt = 0; nt < 2; ++nt)
            #pragma unroll
            for (int ks = 0; ks < 2; ++ks)
                b[nt][ks] = *(const bf16x8*)(sO + (ig * 32 + nt * 16 + l15) * 72 + ks * 32 + q4 * 8);
        #pragma unroll
        for (int mt = 0; mt < 4; ++mt)
            #pragma unroll
            for (int nt = 0; nt < 2; ++nt) {
                acc[mt][nt] = __builtin_amdgcn_mfma_f32_16x16x32_bf16(a[mt][0], b[nt][0], acc[mt][nt], 0, 0, 0);
                acc[mt][nt] = __builtin_amdgcn_mfma_f32_16x16x32_bf16(a[mt][1], b[nt][1], acc[mt][nt], 0, 0, 0);
            }
    }

    const float* gp = g + ((size_t)n * CIN) * HW;
    float* op = out + ((size_t)n * CIN) * HW;
    #pragma unroll
    for (int mt = 0; mt < 4; ++mt) {
        const int co = w * 64 + mt * 16 + q4 * 4;
        const float c0 = batt[co], c1 = batt[co + 1], c2 = batt[co + 2], c3 = batt[co + 3];
        #pragma unroll
        for (int nt = 0; nt < 2; ++nt) {
            const int pos = jbase + nt * 16 + l15;
            const float g0 = gp[(co + 0) * HW + pos], g1 = gp[(co + 1) * HW + pos];
            const float g2 = gp[(co + 2) * HW + pos], g3 = gp[(co + 3) * HW + pos];
            op[(co + 0) * HW + pos] = g0 * (acc[mt][nt].x * invZ + c0 + 1.0f);
            op[(co + 1) * HW + pos] = g1 * (acc[mt][nt].y * invZ + c1 + 1.0f);
            op[(co + 2) * HW + pos] = g2 * (acc[mt][nt].z * invZ + c2 + 1.0f);
            op[(co + 3) * HW + pos] = g3 * (acc[mt][nt].w * invZ + c3 + 1.0f);
        }
    }
}

extern "C" void kernel_launch(void* const* d_in, const int* in_sizes, int n_in,
                              void* d_out, int out_size, void* d_ws, size_t ws_size,
                              hipStream_t stream) {
    const float* x    = (const float*)d_in[0];
    const float* g    = (const float*)d_in[1];
    const float* Wq   = (const float*)d_in[2];
    const float* bq   = (const float*)d_in[3];
    const float* Wk   = (const float*)d_in[4];
    const float* bk   = (const float*)d_in[5];
    const float* Wv   = (const float*)d_in[6];
    const float* bv   = (const float*)d_in[7];
    const float* Watt = (const float*)d_in[8];
    const float* batt = (const float*)d_in[9];
    float* out = (float*)d_out;

    char* ws = (char*)d_ws;
    const size_t qkv_sz = (size_t)NB * HW * CRED * sizeof(bf16);   // 4,718,592 B
    bf16*  qT  = (bf16*)(ws);
    bf16*  kT  = (bf16*)(ws + qkv_sz);
    bf16*  vv  = (bf16*)(ws + 2 * qkv_sz);
    bf16*  OTp = (bf16*)(ws + 3 * qkv_sz);                         // NIG x 4,718,592 B
    char*  w2  = ws + (3 + NIG) * qkv_sz;
    float* Zp  = (float*)(w2);
    bf16*  Wqb = (bf16*)(w2 + 256);
    bf16*  Wkb = Wqb + CRED * CIN;
    bf16*  Wvb = Wkb + CRED * CIN;
    bf16*  Wab = Wvb + CRED * CIN;
    float* bqs = (float*)(Wab + CIN * CRED);

    hipMemsetAsync(Zp, 0, NB * sizeof(float), stream);

    prep_kernel<<<dim3(64), dim3(256), 0, stream>>>(Wq, bq, Wk, Wv, Watt, Wqb, Wkb, Wvb, Wab, bqs);
    qkv_kernel<<<dim3(HW / 32, NB), dim3(256), 0, stream>>>(x, Wqb, bqs, Wkb, bk, Wvb, bv, qT, kT, vv);
    attn_kernel<<<dim3(HW / 64, NIG, NB), dim3(256), 0, stream>>>(qT, kT, vv, OTp, Zp);
    out_kernel<<<dim3(HW / 32, NB), dim3(256), 0, stream>>>(OTp, Zp, Wab, batt, g, out);
}